// Round 8
// baseline (19.673 us; speedup 1.0000x reference)
//
#include <hip/hip_runtime.h>

// DemandMap: collapses the JAX raster to a per-column 1-D stencil.
// binW = binH = 1, integer site coords, sx <= 1: a site of type t at (x,c)
// contributes wx_t * clamp(sy_t - k, 0, 1) to bin (x, c+k).
// Output flat layout (i*nby + j) == stm flat layout (r*height + c).
//
// PERSISTENT MAP-SLICE BLOCKS: 1024 workgroups; block b owns a contiguous
// slice (n4/256 float4-groups) of map b>>8. Map is block-uniform -> no
// divergence, weights in scalar regs. Each block loops ~16 iterations,
// one lane-contiguous nontemporal store per iteration, walking a 256KB
// contiguous window of ONE map == the 6.7 TB/s fill-kernel pattern
// (single write front + persistence; round-7 lesson: single front without
// persistence is not enough). stm loads software-pipelined one iteration
// ahead. Input (16.8 MB) is L3-resident so the 4x read issue stays cheap.
//   c = sum_k w_t[k] * (s[e-k] == t),  w_t[k] = clamp(sy_t - k, 0, 1).

typedef float v4f __attribute__((ext_vector_type(4)));

__global__ __launch_bounds__(256) void demand_map_kernel(
    const int* __restrict__ stm,
    const float* __restrict__ nsx,
    const float* __restrict__ nsy,
    const int* __restrict__ heightP,
    const int* __restrict__ nbxP, const int* __restrict__ nbyP,
    const int* __restrict__ xlP, const int* __restrict__ xhP,
    const int* __restrict__ ylP, const int* __restrict__ yhP,
    float* __restrict__ out,
    int total)                      // W*H site count (== nbx*nby here)
{
    const int n4  = total >> 2;             // float4 / int4 groups per map
    const int map = blockIdx.x >> 8;        // 0..3, block-uniform
    const int slc = blockIdx.x & 255;       // slice within the map
    const int sliceGroups = (n4 + 255) >> 8;
    const int base = slc * sliceGroups;
    const int end  = min(base + sliceGroups, n4);
    if (base >= n4) return;

    const int height = *heightP;            // row length
    const float binArea =
        ((float)(*xhP - *xlP) / (float)(*nbxP)) *
        ((float)(*yhP - *ylP) / (float)(*nbyP));

    // Block-uniform type + weights. Maps 0,1 -> type 1 (idx 0);
    // map 2 -> type 2 (idx 2); map 3 -> type 3 (idx 3).
    const int t    = (map <= 1) ? 1 : map;
    const int sidx = (map <= 1) ? 0 : map;
    const float wx = fminf(nsx[sidx], 1.0f);   // x-overlap = sx for sx<=1
    const float sy = nsy[sidx];
    float w[5];                                // taps k=0..4 (max window 5)
    #pragma unroll
    for (int k = 0; k < 5; ++k) w[k] = fminf(fmaxf(sy - (float)k, 0.0f), 1.0f);

    const int4* stm4 = (const int4*)stm;
    v4f* out4 = (v4f*)out;
    const long long mapOff = (long long)map * n4;

    // Software-pipelined walk: load iteration it+1 before computing it.
    int g = base + (int)threadIdx.x;
    int4 cur  = make_int4(0, 0, 0, 0);
    int4 prev = make_int4(0, 0, 0, 0);
    if (g < end) {
        cur = stm4[g];
        if (((g << 2) % height) != 0) prev = stm4[g - 1];
    }

    while (g < end) {
        const int gn = g + 256;
        int4 ncur  = make_int4(0, 0, 0, 0);
        int4 nprev = make_int4(0, 0, 0, 0);
        if (gn < end) {
            ncur = stm4[gn];
            if (((gn << 2) % height) != 0) nprev = stm4[gn - 1];
        }

        // s[0..3] = y0-4..y0-1, s[4..7] = y0..y0+3
        int s[8] = { prev.x, prev.y, prev.z, prev.w,
                     cur.x,  cur.y,  cur.z,  cur.w };

        float o[4];
        #pragma unroll
        for (int e = 0; e < 4; ++e) {
            float c = 0.0f;
            #pragma unroll
            for (int k = 0; k < 5; ++k)
                c += w[k] * (float)(s[4 + e - k] == t);
            o[e] = binArea - wx * c;
        }

        const v4f v = { o[0], o[1], o[2], o[3] };
        __builtin_nontemporal_store(v, &out4[mapOff + g]);

        cur = ncur; prev = nprev; g = gn;
    }
}

extern "C" void kernel_launch(void* const* d_in, const int* in_sizes, int n_in,
                              void* d_out, int out_size, void* d_ws, size_t ws_size,
                              hipStream_t stream) {
    const int*   stm = (const int*)  d_in[0];
    const float* nsx = (const float*)d_in[1];
    const float* nsy = (const float*)d_in[2];
    // d_in[3]=width, d_in[4]=height, d_in[5]=nbx, d_in[6]=nby,
    // d_in[7]=xl, d_in[8]=xh, d_in[9]=yl, d_in[10]=yh (int32 scalars on device)
    const int* heightP = (const int*)d_in[4];
    const int* nbxP    = (const int*)d_in[5];
    const int* nbyP    = (const int*)d_in[6];
    const int* xlP     = (const int*)d_in[7];
    const int* xhP     = (const int*)d_in[8];
    const int* ylP     = (const int*)d_in[9];
    const int* yhP     = (const int*)d_in[10];

    float* out = (float*)d_out;
    const int total = in_sizes[0];          // W*H == per-map element count

    // 4 maps x 256 slices; map id is block-uniform.
    demand_map_kernel<<<1024, 256, 0, stream>>>(
        stm, nsx, nsy, heightP, nbxP, nbyP, xlP, xhP, ylP, yhP, out, total);
}

// Round 9
// 17.403 us; speedup vs baseline: 1.1305x; 1.1305x over previous
//
#include <hip/hip_runtime.h>

// DemandMap: collapses the JAX raster to a per-column 1-D stencil.
// binW = binH = 1, integer site coords, sx <= 1: a site of type t at (x,c)
// contributes wx_t * clamp(sy_t - k, 0, 1) to bin (x, c+k).
// Output flat layout (i*nby + j) == stm flat layout (r*height + c).
//
// R5 structure (best: 17.4us): block b owns 512 consecutive float4-groups,
// thread t handles base+t and base+256+t; every store lane-contiguous;
// nontemporal stores (write-once outputs, keep L2/L3 for stm).
// NEW: map-major store order -- each map's two 1KB wave-stores issue
// back-to-back at consecutive addresses (one sequential page burst per
// write front) instead of alternating across the 4 maps twice.

typedef float v4f __attribute__((ext_vector_type(4)));

__global__ __launch_bounds__(256) void demand_map_kernel(
    const int* __restrict__ stm,
    const float* __restrict__ nsx,
    const float* __restrict__ nsy,
    const int* __restrict__ heightP,
    const int* __restrict__ nbxP, const int* __restrict__ nbyP,
    const int* __restrict__ xlP, const int* __restrict__ xhP,
    const int* __restrict__ ylP, const int* __restrict__ yhP,
    float* __restrict__ out,
    int total)                      // W*H site count (== nbx*nby here)
{
    const int n4 = total >> 2;      // float4 / int4 groups per map
    const int base = blockIdx.x * 512;
    const int g0 = base + threadIdx.x;
    const int g1 = g0 + 256;
    if (g0 >= n4) return;
    const bool do1 = (g1 < n4);

    const int height = *heightP;    // row length; height % 4 == 0
    const float binArea =
        ((float)(*xhP - *xlP) / (float)(*nbxP)) *
        ((float)(*yhP - *ylP) / (float)(*nbyP));

    // x-overlap weight = sx (sx<=1); y-taps w[k] = clamp(sy-k, 0, 1)
    const float wx1 = fminf(nsx[0], 1.0f);
    const float wx2 = fminf(nsx[2], 1.0f);
    const float wx3 = fminf(nsx[3], 1.0f);
    const float sy1 = nsy[0], sy2 = nsy[2], sy3 = nsy[3];
    float w1[2], w2[4], w3[5];
    #pragma unroll
    for (int k = 0; k < 2; ++k) w1[k] = fminf(fmaxf(sy1 - (float)k, 0.0f), 1.0f);
    #pragma unroll
    for (int k = 0; k < 4; ++k) w2[k] = fminf(fmaxf(sy2 - (float)k, 0.0f), 1.0f);
    #pragma unroll
    for (int k = 0; k < 5; ++k) w3[k] = fminf(fmaxf(sy3 - (float)k, 0.0f), 1.0f);

    const int4* stm4 = (const int4*)stm;

    // Issue all global loads up front (2x memory-level parallelism).
    const int4 curA = stm4[g0];
    int4 prevA = make_int4(0, 0, 0, 0);
    if (((g0 << 2) % height) != 0) prevA = stm4[g0 - 1];
    int4 curB = make_int4(0, 0, 0, 0), prevB = make_int4(0, 0, 0, 0);
    if (do1) {
        curB = stm4[g1];
        if (((g1 << 2) % height) != 0) prevB = stm4[g1 - 1];
    }

    // Compute both windows fully into registers before any store.
    v4f v0[2], v2[2], v3[2];
    #pragma unroll
    for (int it = 0; it < 2; ++it) {
        const int4 cur  = (it == 0) ? curA  : curB;
        const int4 prev = (it == 0) ? prevA : prevB;

        // s[0..3] = y0-4..y0-1, s[4..7] = y0..y0+3
        int s[8] = { prev.x, prev.y, prev.z, prev.w,
                     cur.x,  cur.y,  cur.z,  cur.w };

        float o0[4], o2[4], o3[4];
        #pragma unroll
        for (int e = 0; e < 4; ++e) {
            float c0 = w1[0] * (float)(s[4 + e] == 1)
                     + w1[1] * (float)(s[3 + e] == 1);
            float c2 = w2[0] * (float)(s[4 + e] == 2)
                     + w2[1] * (float)(s[3 + e] == 2)
                     + w2[2] * (float)(s[2 + e] == 2)
                     + w2[3] * (float)(s[1 + e] == 2);
            float c3 = w3[0] * (float)(s[4 + e] == 3)
                     + w3[1] * (float)(s[3 + e] == 3)
                     + w3[2] * (float)(s[2 + e] == 3)
                     + w3[3] * (float)(s[1 + e] == 3)
                     + w3[4] * (float)(s[0 + e] == 3);
            o0[e] = binArea - wx1 * c0;
            o2[e] = binArea - wx2 * c2;
            o3[e] = binArea - wx3 * c3;
        }
        v0[it] = (v4f){ o0[0], o0[1], o0[2], o0[3] };
        v2[it] = (v4f){ o2[0], o2[1], o2[2], o2[3] };
        v3[it] = (v4f){ o3[0], o3[1], o3[2], o3[3] };
    }

    v4f* out4 = (v4f*)out;

    // Map-major store order: two consecutive-address wave-stores per front.
    __builtin_nontemporal_store(v0[0], &out4[g0]);                 // map0
    if (do1) __builtin_nontemporal_store(v0[1], &out4[g1]);
    __builtin_nontemporal_store(v0[0], &out4[n4 + g0]);            // map1 (alias)
    if (do1) __builtin_nontemporal_store(v0[1], &out4[n4 + g1]);
    __builtin_nontemporal_store(v2[0], &out4[2 * n4 + g0]);        // map2
    if (do1) __builtin_nontemporal_store(v2[1], &out4[2 * n4 + g1]);
    __builtin_nontemporal_store(v3[0], &out4[3 * n4 + g0]);        // map3
    if (do1) __builtin_nontemporal_store(v3[1], &out4[3 * n4 + g1]);
}

extern "C" void kernel_launch(void* const* d_in, const int* in_sizes, int n_in,
                              void* d_out, int out_size, void* d_ws, size_t ws_size,
                              hipStream_t stream) {
    const int*   stm = (const int*)  d_in[0];
    const float* nsx = (const float*)d_in[1];
    const float* nsy = (const float*)d_in[2];
    // d_in[3]=width, d_in[4]=height, d_in[5]=nbx, d_in[6]=nby,
    // d_in[7]=xl, d_in[8]=xh, d_in[9]=yl, d_in[10]=yh (int32 scalars on device)
    const int* heightP = (const int*)d_in[4];
    const int* nbxP    = (const int*)d_in[5];
    const int* nbyP    = (const int*)d_in[6];
    const int* xlP     = (const int*)d_in[7];
    const int* xhP     = (const int*)d_in[8];
    const int* ylP     = (const int*)d_in[9];
    const int* yhP     = (const int*)d_in[10];

    float* out = (float*)d_out;
    const int total = in_sizes[0];          // W*H == per-map element count
    const int n4 = total >> 2;
    const int blocks = (n4 + 511) / 512;    // 512 groups per block (x2 unroll)

    demand_map_kernel<<<blocks, 256, 0, stream>>>(
        stm, nsx, nsy, heightP, nbxP, nbyP, xlP, xhP, ylP, yhP, out, total);
}